// Round 14
// baseline (850.456 us; speedup 1.0000x reference)
//
#include <hip/hip_runtime.h>

// GCN layer: out = ReLU(BN(GCNConv(x) + x@skip_W))
// R14: R13 logic, layout re-audited (R13 repeated R11's u under-allocation:
//      ushort elems / 2 = float slots; u = 3,203,072 floats, NOT 1,601,536).
//      Sort-free: per-bucket LDS fp32 accumulation over unsorted binned edges.

typedef unsigned short ushort;
typedef __bf16 bf16x8 __attribute__((ext_vector_type(8)));
typedef float f32x4 __attribute__((ext_vector_type(4)));
typedef float f32x2 __attribute__((ext_vector_type(2)));

constexpr int N_NODES = 100000;
constexpr int N_PAD   = 100096;                  // 782*128
constexpr int E_EDGES = 1600000;

constexpr int BUCK_SHIFT = 7;                    // 128 nodes per bucket
constexpr int NBUCK   = (N_NODES + 127) / 128;   // 782
constexpr int NBUCK_P = 784;
constexpr int CHUNK   = 8192;
constexpr int NCHUNK  = (E_EDGES + CHUNK - 1) / CHUNK;  // 196
constexpr int GH_STRIDE = 200;

// ws layout (4-byte element offsets) — audited, end = start + size:
//   scale  @0        size 256        -> 256
//   dinv   @256      size 100,096    -> 100,352
//   base   @100,352  size 800        -> 101,152
//   gh_t   @101,152  size 156,800    -> 257,952
//   binned @257,952  size 1,600,000  -> 1,857,952  (partial 200,192 aliases; binned dead post-agg)
//   u      @1,857,952 size 3,203,072 -> 5,061,024  (N_PAD*64 ushort / 2)
//   pre    @5,061,024 size 6,406,144 -> 11,467,168 (N_PAD*128 ushort / 2;
//          xd8 1,601,536 uints aliases pre, dead before gemm writes pre)
//   Bt     @11,467,168 size 8,192    -> 11,475,360
constexpr size_t OFF_SCALE  = 0;
constexpr size_t OFF_DINV   = 256;
constexpr size_t OFF_BASE   = 100352;
constexpr size_t OFF_GHIST  = 101152;
constexpr size_t OFF_BINNED = 257952;
constexpr size_t OFF_PART   = OFF_BINNED;
constexpr size_t OFF_U      = 1857952;
constexpr size_t OFF_PRE    = 5061024;
constexpr size_t OFF_XD8    = OFF_PRE;
constexpr size_t OFF_BT     = 11467168;

static __device__ __forceinline__ ushort f2bf(float f) {
    union { float f; unsigned u; } v; v.f = f;
    unsigned r = v.u + 0x7FFFu + ((v.u >> 16) & 1u);  // RNE
    return (ushort)(r >> 16);
}
static __device__ __forceinline__ float bf2f(ushort u) {
    union { unsigned u; float f; } v; v.u = (unsigned)u << 16;
    return v.f;
}
static __device__ __forceinline__ unsigned pack_fp8x4(float a, float b, float c, float d) {
    int r = 0;
    r = __builtin_amdgcn_cvt_pk_fp8_f32(a, b, r, false);
    r = __builtin_amdgcn_cvt_pk_fp8_f32(c, d, r, true);
    return (unsigned)r;
}
static __device__ __forceinline__ bf16x8 pack_bf8(float4 a, float4 b) {
    union { ushort us[8]; bf16x8 v; } u;
    u.us[0] = f2bf(a.x); u.us[1] = f2bf(a.y); u.us[2] = f2bf(a.z); u.us[3] = f2bf(a.w);
    u.us[4] = f2bf(b.x); u.us[5] = f2bf(b.y); u.us[6] = f2bf(b.z); u.us[7] = f2bf(b.w);
    return u.v;
}

// ---- hist (blocks 0..NCHUNK-1, transposed write) + Bt prep (last 64 blocks) ----
__global__ __launch_bounds__(256) void k_hist(const int* __restrict__ col,
                                              int* __restrict__ gh_t,
                                              const float* __restrict__ W,
                                              const float* __restrict__ skipW,
                                              ushort* __restrict__ Bt) {
    int c = blockIdx.x, t = threadIdx.x;
    if (c >= NCHUNK) {  // prep: Bt[n][k] = bf16(B[k][n])
        int idx = (c - NCHUNK) * 256 + t;
        int k = idx >> 7, n = idx & 127;
        float v = (k < 64) ? W[k * 128 + n] : skipW[(k - 64) * 128 + n];
        Bt[n * 128 + k] = f2bf(v);
        return;
    }
    __shared__ int h[NBUCK_P];
    for (int b = t; b < NBUCK_P; b += 256) h[b] = 0;
    __syncthreads();
    const int4* col4 = (const int4*)col;
    int g0 = c * (CHUNK / 4);
#pragma unroll
    for (int i = 0; i < CHUNK / 1024; ++i) {
        int g4 = g0 + i * 256 + t;
        if (g4 * 4 + 3 < E_EDGES) {
            int4 cc = col4[g4];
            atomicAdd(&h[cc.x >> BUCK_SHIFT], 1);
            atomicAdd(&h[cc.y >> BUCK_SHIFT], 1);
            atomicAdd(&h[cc.z >> BUCK_SHIFT], 1);
            atomicAdd(&h[cc.w >> BUCK_SHIFT], 1);
        } else {
#pragma unroll
            for (int j = 0; j < 4; ++j) {
                int e = g4 * 4 + j;
                if (e < E_EDGES) atomicAdd(&h[col[e] >> BUCK_SHIFT], 1);
            }
        }
    }
    __syncthreads();
    for (int b = t; b < NBUCK_P; b += 256) gh_t[(size_t)b * GH_STRIDE + c] = h[b];
}

// ---- wave-per-bucket exclusive scan over chunks (contiguous, barrier-free) ----
__global__ __launch_bounds__(256) void k_scan_chunks(int* __restrict__ gh_t,
                                                     int* __restrict__ base) {
    int w = threadIdx.x >> 6, l = threadIdx.x & 63;
    int b = blockIdx.x * 4 + w;          // 196 blocks x 4 waves = 784
    if (b >= NBUCK_P) return;
    int* rowp = gh_t + (size_t)b * GH_STRIDE;
    int carry = 0;
#pragma unroll
    for (int i = 0; i < 4; ++i) {        // 4*64 = 256 >= NCHUNK
        int idx = i * 64 + l;
        int v = (idx < NCHUNK) ? rowp[idx] : 0;
        int orig = v;
#pragma unroll
        for (int d = 1; d < 64; d <<= 1) {
            int o = __shfl_up(v, d);
            if (l >= d) v += o;
        }
        if (idx < NCHUNK) rowp[idx] = carry + v - orig;  // exclusive
        carry += __shfl(v, 63);
    }
    if (l == 0 && b < NBUCK) base[b] = carry;            // bucket total
}

// ---- exclusive scan of bucket totals -> bucket bases ----
__global__ __launch_bounds__(1024) void k_scan_bases(int* __restrict__ base) {
    __shared__ int lds[1024];
    int t = threadIdx.x;
    int v = (t < NBUCK) ? base[t] : 0;
    lds[t] = v;
    __syncthreads();
    int val = v;
#pragma unroll
    for (int off = 1; off < 1024; off <<= 1) {
        int add = (t >= off) ? lds[t - off] : 0;
        __syncthreads();
        val += add;
        lds[t] = val;
        __syncthreads();
    }
    if (t < NBUCK) base[t] = val - v;
    if (t == 1023) base[NBUCK] = val;
}

// ---- scatter edges into bucket-contiguous array (packed), int4 reads ----
__global__ __launch_bounds__(256) void k_scatter_bin(const int* __restrict__ row,
                                                     const int* __restrict__ col,
                                                     const int* __restrict__ gh_t,
                                                     const int* __restrict__ base,
                                                     unsigned int* __restrict__ binned) {
    __shared__ int cur[NBUCK_P];
    int c = blockIdx.x, t = threadIdx.x;
    for (int b = t; b < NBUCK_P; b += 256) {
        int bb = (b < NBUCK) ? base[b] : 0;
        cur[b] = bb + gh_t[(size_t)b * GH_STRIDE + c];
    }
    __syncthreads();
    const int4* col4 = (const int4*)col;
    const int4* row4 = (const int4*)row;
    int g0 = c * (CHUNK / 4);
#pragma unroll
    for (int i = 0; i < CHUNK / 1024; ++i) {
        int g4 = g0 + i * 256 + t;
        if (g4 * 4 + 3 < E_EDGES) {
            int4 cc = col4[g4];
            int4 rr = row4[g4];
            int p;
            p = atomicAdd(&cur[cc.x >> BUCK_SHIFT], 1);
            binned[p] = ((unsigned)(cc.x & 127) << 17) | (unsigned)rr.x;
            p = atomicAdd(&cur[cc.y >> BUCK_SHIFT], 1);
            binned[p] = ((unsigned)(cc.y & 127) << 17) | (unsigned)rr.y;
            p = atomicAdd(&cur[cc.z >> BUCK_SHIFT], 1);
            binned[p] = ((unsigned)(cc.z & 127) << 17) | (unsigned)rr.z;
            p = atomicAdd(&cur[cc.w >> BUCK_SHIFT], 1);
            binned[p] = ((unsigned)(cc.w & 127) << 17) | (unsigned)rr.w;
        } else {
#pragma unroll
            for (int j = 0; j < 4; ++j) {
                int e = g4 * 4 + j;
                if (e < E_EDGES) {
                    int d = col[e], s = row[e];
                    int p = atomicAdd(&cur[d >> BUCK_SHIFT], 1);
                    binned[p] = ((unsigned)(d & 127) << 17) | (unsigned)s;
                }
            }
        }
    }
}

// ---- per-bucket prep: degree count -> dinv; fused fp8 cast xd8 = fp8(x*dinv) ----
__global__ __launch_bounds__(256) void k_prep_bucket(const unsigned int* __restrict__ binned,
                                                     const int* __restrict__ base,
                                                     float* __restrict__ dinv,
                                                     const float* __restrict__ x,
                                                     unsigned* __restrict__ xd8) {
    __shared__ int lcnt[128];
    __shared__ float ldinv[128];
    int b = blockIdx.x, t = threadIdx.x;
    int i0 = base[b], i1 = base[b + 1];
    int cnt = i1 - i0;
    int n0 = b << BUCK_SHIFT;
    int nn = min(128, N_NODES - n0);

    if (t < 128) lcnt[t] = 0;
    __syncthreads();
    for (int k = t; k < cnt; k += 256)
        atomicAdd(&lcnt[binned[i0 + k] >> 17], 1);
    __syncthreads();
    if (t < 128) {
        float dv = rsqrtf((float)lcnt[t] + 1.0f);  // +1 self loop
        ldinv[t] = dv;
        if (t < nn) dinv[n0 + t] = dv;
    }
    __syncthreads();
#pragma unroll
    for (int it = 0; it < 8; ++it) {
        int idx = it * 256 + t;          // 0..2047
        int nl = idx >> 4, q = idx & 15;
        int c = n0 + nl;
        unsigned w8 = 0;
        if (nl < nn) {
            float4 v = ((const float4*)x)[(size_t)c * 16 + q];
            float d = ldinv[nl];
            w8 = pack_fp8x4(v.x * d, v.y * d, v.z * d, v.w * d);
        }
        xd8[(size_t)c * 16 + q] = w8;
    }
}

// ---- per-bucket aggregation: LDS fp32 accumulator, unsorted edges ----
__global__ __launch_bounds__(256) void k_agg_bucket(const unsigned int* __restrict__ binned,
                                                    const int* __restrict__ base,
                                                    const unsigned* __restrict__ xd8,
                                                    const float* __restrict__ dinv,
                                                    ushort* __restrict__ u) {
    __shared__ float accf[128 * 64];     // 32 KB
    int b = blockIdx.x, t = threadIdx.x;
    int i0 = base[b], i1 = base[b + 1];
    int n0 = b << BUCK_SHIFT;
    int nn = min(128, N_NODES - n0);
    int g = t >> 4, q = t & 15;          // 16 groups of 16 lanes

    for (int k = t; k < 128 * 64; k += 256) accf[k] = 0.f;
    __syncthreads();

    int i = i0 + g;
    for (; i + 48 < i1; i += 64) {
        unsigned e0 = binned[i],      e1 = binned[i + 16];
        unsigned e2 = binned[i + 32], e3 = binned[i + 48];
        unsigned w0 = xd8[(e0 & 0x1FFFF) * 16 + q];
        unsigned w1 = xd8[(e1 & 0x1FFFF) * 16 + q];
        unsigned w2 = xd8[(e2 & 0x1FFFF) * 16 + q];
        unsigned w3 = xd8[(e3 & 0x1FFFF) * 16 + q];
        int d0 = (int)(e0 >> 17), d1 = (int)(e1 >> 17);
        int d2 = (int)(e2 >> 17), d3 = (int)(e3 >> 17);
        f32x2 lo, hi;
        lo = __builtin_amdgcn_cvt_pk_f32_fp8((int)w0, false);
        hi = __builtin_amdgcn_cvt_pk_f32_fp8((int)w0, true);
        atomicAdd(&accf[d0 * 64 + q * 4 + 0], lo.x);
        atomicAdd(&accf[d0 * 64 + q * 4 + 1], lo.y);
        atomicAdd(&accf[d0 * 64 + q * 4 + 2], hi.x);
        atomicAdd(&accf[d0 * 64 + q * 4 + 3], hi.y);
        lo = __builtin_amdgcn_cvt_pk_f32_fp8((int)w1, false);
        hi = __builtin_amdgcn_cvt_pk_f32_fp8((int)w1, true);
        atomicAdd(&accf[d1 * 64 + q * 4 + 0], lo.x);
        atomicAdd(&accf[d1 * 64 + q * 4 + 1], lo.y);
        atomicAdd(&accf[d1 * 64 + q * 4 + 2], hi.x);
        atomicAdd(&accf[d1 * 64 + q * 4 + 3], hi.y);
        lo = __builtin_amdgcn_cvt_pk_f32_fp8((int)w2, false);
        hi = __builtin_amdgcn_cvt_pk_f32_fp8((int)w2, true);
        atomicAdd(&accf[d2 * 64 + q * 4 + 0], lo.x);
        atomicAdd(&accf[d2 * 64 + q * 4 + 1], lo.y);
        atomicAdd(&accf[d2 * 64 + q * 4 + 2], hi.x);
        atomicAdd(&accf[d2 * 64 + q * 4 + 3], hi.y);
        lo = __builtin_amdgcn_cvt_pk_f32_fp8((int)w3, false);
        hi = __builtin_amdgcn_cvt_pk_f32_fp8((int)w3, true);
        atomicAdd(&accf[d3 * 64 + q * 4 + 0], lo.x);
        atomicAdd(&accf[d3 * 64 + q * 4 + 1], lo.y);
        atomicAdd(&accf[d3 * 64 + q * 4 + 2], hi.x);
        atomicAdd(&accf[d3 * 64 + q * 4 + 3], hi.y);
    }
    for (; i < i1; i += 16) {
        unsigned e = binned[i];
        unsigned w = xd8[(e & 0x1FFFF) * 16 + q];
        int d = (int)(e >> 17);
        f32x2 lo = __builtin_amdgcn_cvt_pk_f32_fp8((int)w, false);
        f32x2 hi = __builtin_amdgcn_cvt_pk_f32_fp8((int)w, true);
        atomicAdd(&accf[d * 64 + q * 4 + 0], lo.x);
        atomicAdd(&accf[d * 64 + q * 4 + 1], lo.y);
        atomicAdd(&accf[d * 64 + q * 4 + 2], hi.x);
        atomicAdd(&accf[d * 64 + q * 4 + 3], hi.y);
    }
    __syncthreads();

    // finalize: u[c] = bf16( dinv[c] * (accf[nl] + self xd8[c]) )
#pragma unroll
    for (int it = 0; it < 8; ++it) {
        int idx = it * 256 + t;
        int nl = idx >> 4, q2 = idx & 15;
        int c = n0 + nl;
        ushort4 o = {0, 0, 0, 0};
        if (nl < nn) {
            unsigned w = xd8[(size_t)c * 16 + q2];
            f32x2 lo = __builtin_amdgcn_cvt_pk_f32_fp8((int)w, false);
            f32x2 hi = __builtin_amdgcn_cvt_pk_f32_fp8((int)w, true);
            float dv = dinv[c];
            o.x = f2bf((accf[nl * 64 + q2 * 4 + 0] + lo.x) * dv);
            o.y = f2bf((accf[nl * 64 + q2 * 4 + 1] + lo.y) * dv);
            o.z = f2bf((accf[nl * 64 + q2 * 4 + 2] + hi.x) * dv);
            o.w = f2bf((accf[nl * 64 + q2 * 4 + 3] + hi.y) * dv);
        }
        *(ushort4*)&u[(size_t)c * 64 + q2 * 4] = o;
    }
}

// ---- MFMA GEMM: pre = [u | bf16(x)] @ Bt^T + bias (bf16 out); BN partials ----
__global__ __launch_bounds__(256) void k_gemm(const ushort* __restrict__ u,
                                              const float* __restrict__ x,
                                              const ushort* __restrict__ Bt,
                                              const float* __restrict__ bias,
                                              ushort* __restrict__ pre,
                                              float* __restrict__ partial) {
    __shared__ float sred[128];
    __shared__ float qred[128];
    int tid = threadIdx.x;
    int wave = tid >> 6, lane = tid & 63;
    int wm = wave >> 1, wn = wave & 1;
    int l15 = lane & 15, quad = lane >> 4;
    int row0 = blockIdx.x * 128 + wm * 64;
    int col0 = wn * 64;

    if (tid < 128) { sred[tid] = 0.f; qred[tid] = 0.f; }
    __syncthreads();

    bf16x8 af[4][4], bf_[4][4];
#pragma unroll
    for (int kc = 0; kc < 2; ++kc) {
        int ko = kc * 32 + quad * 8;
#pragma unroll
        for (int im = 0; im < 4; ++im)
            af[kc][im] = *(const bf16x8*)&u[(size_t)(row0 + im * 16 + l15) * 64 + ko];
    }
#pragma unroll
    for (int kc = 2; kc < 4; ++kc) {
        int ko = (kc - 2) * 32 + quad * 8;
#pragma unroll
        for (int im = 0; im < 4; ++im) {
            int r = row0 + im * 16 + l15;
            float4 v0 = make_float4(0.f, 0.f, 0.f, 0.f);
            float4 v1 = v0;
            if (r < N_NODES) {
                v0 = *(const float4*)&x[(size_t)r * 64 + ko];
                v1 = *(const float4*)&x[(size_t)r * 64 + ko + 4];
            }
            af[kc][im] = pack_bf8(v0, v1);
        }
    }
#pragma unroll
    for (int kc = 0; kc < 4; ++kc)
#pragma unroll
        for (int jn = 0; jn < 4; ++jn)
            bf_[kc][jn] = *(const bf16x8*)&Bt[(size_t)(col0 + jn * 16 + l15) * 128 + kc * 32 + quad * 8];

    f32x4 acc[4][4];
#pragma unroll
    for (int a = 0; a < 4; ++a)
#pragma unroll
        for (int b = 0; b < 4; ++b) acc[a][b] = (f32x4){0.f, 0.f, 0.f, 0.f};

#pragma unroll
    for (int kc = 0; kc < 4; ++kc)
#pragma unroll
        for (int im = 0; im < 4; ++im)
#pragma unroll
            for (int jn = 0; jn < 4; ++jn)
                acc[im][jn] = __builtin_amdgcn_mfma_f32_16x16x32_bf16(
                    af[kc][im], bf_[kc][jn], acc[im][jn], 0, 0, 0);

    int coln[4];
    float bi[4];
#pragma unroll
    for (int jn = 0; jn < 4; ++jn) {
        coln[jn] = col0 + jn * 16 + l15;
        bi[jn] = bias[coln[jn]];
    }
    float lsum[4] = {0.f, 0.f, 0.f, 0.f};
    float lsq[4]  = {0.f, 0.f, 0.f, 0.f};
#pragma unroll
    for (int im = 0; im < 4; ++im) {
        int rbase = row0 + im * 16 + quad * 4;
#pragma unroll
        for (int r = 0; r < 4; ++r) {
            int rowi = rbase + r;
            if (rowi < N_NODES) {
#pragma unroll
                for (int jn = 0; jn < 4; ++jn) {
                    float v = acc[im][jn][r] + bi[jn];
                    pre[(size_t)rowi * 128 + coln[jn]] = f2bf(v);
                    lsum[jn] += v;
                    lsq[jn]  += v * v;
                }
            }
        }
    }
#pragma unroll
    for (int jn = 0; jn < 4; ++jn) {
        atomicAdd(&sred[coln[jn]], lsum[jn]);
        atomicAdd(&qred[coln[jn]], lsq[jn]);
    }
    __syncthreads();
    if (tid < 128) {
        partial[(size_t)blockIdx.x * 256 + tid]       = sred[tid];
        partial[(size_t)blockIdx.x * 256 + 128 + tid] = qred[tid];
    }
}

// ---- reduce 782 partials -> scale/shift (one block per output column) ----
__global__ __launch_bounds__(256) void k_reduce(const float* __restrict__ partial,
                                                const float* __restrict__ gamma,
                                                const float* __restrict__ beta,
                                                float* __restrict__ scaleshift) {
    __shared__ float ls[256], lq[256];
    int j = blockIdx.x;   // 0..127
    int t = threadIdx.x;
    float s = 0.f, q = 0.f;
    for (int p = t; p < NBUCK; p += 256) {
        s += partial[(size_t)p * 256 + j];
        q += partial[(size_t)p * 256 + 128 + j];
    }
    ls[t] = s; lq[t] = q;
    __syncthreads();
#pragma unroll
    for (int off = 128; off > 0; off >>= 1) {
        if (t < off) { ls[t] += ls[t + off]; lq[t] += lq[t + off]; }
        __syncthreads();
    }
    if (t == 0) {
        float mean = ls[0] * (1.0f / N_NODES);
        float var  = lq[0] * (1.0f / N_NODES) - mean * mean;
        float sc   = gamma[j] * rsqrtf(var + 1e-5f);
        scaleshift[j]       = sc;
        scaleshift[128 + j] = beta[j] - mean * sc;
    }
}

// read bf16 pre, write fp32 out
__global__ void k_apply(const ushort* __restrict__ pre, float* __restrict__ out,
                        const float* __restrict__ scaleshift) {
    int t = blockIdx.x * blockDim.x + threadIdx.x;
    if (t >= N_NODES * 32) return;
    int j4 = t & 31;
    ushort4 p = ((const ushort4*)pre)[t];
    float4 sc = ((const float4*)scaleshift)[j4];
    float4 sh = ((const float4*)(scaleshift + 128))[j4];
    float4 v;
    v.x = fmaxf(fmaf(bf2f(p.x), sc.x, sh.x), 0.f);
    v.y = fmaxf(fmaf(bf2f(p.y), sc.y, sh.y), 0.f);
    v.z = fmaxf(fmaf(bf2f(p.z), sc.z, sh.z), 0.f);
    v.w = fmaxf(fmaf(bf2f(p.w), sc.w, sh.w), 0.f);
    ((float4*)out)[t] = v;
}

extern "C" void kernel_launch(void* const* d_in, const int* in_sizes, int n_in,
                              void* d_out, int out_size, void* d_ws, size_t ws_size,
                              hipStream_t stream) {
    const float* x      = (const float*)d_in[0];
    const int*   eidx   = (const int*)d_in[1];
    const float* W      = (const float*)d_in[2];
    const float* bias   = (const float*)d_in[3];
    const float* skipW  = (const float*)d_in[4];
    const float* gamma  = (const float*)d_in[5];
    const float* beta   = (const float*)d_in[6];
    float* out = (float*)d_out;
    float* ws  = (float*)d_ws;

    const int* row = eidx;
    const int* col = eidx + E_EDGES;

    float* scaleshift = ws + OFF_SCALE;
    float* dinv       = ws + OFF_DINV;
    int*   base       = (int*)(ws + OFF_BASE);
    int*   gh_t       = (int*)(ws + OFF_GHIST);
    unsigned int* binned = (unsigned int*)(ws + OFF_BINNED);
    float* partial    = ws + OFF_PART;            // aliases binned (dead after agg)
    ushort* u         = (ushort*)(ws + OFF_U);
    unsigned* xd8     = (unsigned*)(ws + OFF_XD8);  // aliases pre (dead by gemm)
    ushort* pre       = (ushort*)(ws + OFF_PRE);
    ushort* Bt        = (ushort*)(ws + OFF_BT);

    k_hist<<<NCHUNK + 64, 256, 0, stream>>>(col, gh_t, W, skipW, Bt);
    k_scan_chunks<<<(NBUCK_P + 3) / 4, 256, 0, stream>>>(gh_t, base);
    k_scan_bases<<<1, 1024, 0, stream>>>(base);
    k_scatter_bin<<<NCHUNK, 256, 0, stream>>>(row, col, gh_t, base, binned);
    k_prep_bucket<<<NBUCK, 256, 0, stream>>>(binned, base, dinv, x, xd8);
    k_agg_bucket<<<NBUCK, 256, 0, stream>>>(binned, base, xd8, dinv, u);
    k_gemm<<<NBUCK, 256, 0, stream>>>(u, x, Bt, bias, pre, partial);
    k_reduce<<<128, 256, 0, stream>>>(partial, gamma, beta, scaleshift);
    k_apply<<<(N_NODES * 32 + 255) / 256, 256, 0, stream>>>(pre, out, scaleshift);
}

// Round 18
// 206.712 us; speedup vs baseline: 4.1142x; 4.1142x over previous
//
#include <hip/hip_runtime.h>

// GCN layer: out = ReLU(BN(GCNConv(x) + x@skip_W))
// R18: resubmit of R12-revert (best passing, 210us). R15-R17 all hit infra
//      failures (GPU acquisition timeout / container) — never ran.
//      Transposed chunk-histogram (wave-shfl scan), CHUNK=8192, gemm
//      converts fp32 x in-register, fp8 gather, hoisted bf16 MFMA GEMM.

typedef unsigned short ushort;
typedef __bf16 bf16x8 __attribute__((ext_vector_type(8)));
typedef float f32x4 __attribute__((ext_vector_type(4)));
typedef float f32x2 __attribute__((ext_vector_type(2)));

constexpr int N_NODES = 100000;
constexpr int N_PAD   = 100096;                  // 782*128
constexpr int E_EDGES = 1600000;

constexpr int BUCK_SHIFT = 7;                    // 128 nodes per bucket
constexpr int NBUCK   = (N_NODES + 127) / 128;   // 782
constexpr int NBUCK_P = 784;
constexpr int CHUNK   = 8192;
constexpr int NCHUNK  = (E_EDGES + CHUNK - 1) / CHUNK;  // 196
constexpr int GH_STRIDE = 200;
constexpr int SORT_CAP = 4096;

// ws layout (4-byte element offsets) — audited (R12's):
constexpr size_t OFF_SCALE  = 0;
constexpr size_t OFF_DINV   = 256;
constexpr size_t OFF_ROWPTR = 100352;
constexpr size_t OFF_BASE   = 200480;
constexpr size_t OFF_GHIST  = 201280;    // ends 358080
constexpr size_t OFF_BINNED = 358080;    // ends 1958080
constexpr size_t OFF_PART   = OFF_BINNED;
constexpr size_t OFF_U      = 1958080;   // ends 5161152 (N_PAD*64 ushort / 2)
constexpr size_t OFF_PRE    = 5161152;   // ends 11567296 (N_PAD*128 ushort / 2)
constexpr size_t OFF_XD8    = OFF_PRE;
constexpr size_t OFF_BT     = 11567296;  // ends 11575488

static __device__ __forceinline__ ushort f2bf(float f) {
    union { float f; unsigned u; } v; v.f = f;
    unsigned r = v.u + 0x7FFFu + ((v.u >> 16) & 1u);  // RNE
    return (ushort)(r >> 16);
}
static __device__ __forceinline__ float bf2f(ushort u) {
    union { unsigned u; float f; } v; v.u = (unsigned)u << 16;
    return v.f;
}
static __device__ __forceinline__ unsigned pack_fp8x4(float a, float b, float c, float d) {
    int r = 0;
    r = __builtin_amdgcn_cvt_pk_fp8_f32(a, b, r, false);
    r = __builtin_amdgcn_cvt_pk_fp8_f32(c, d, r, true);
    return (unsigned)r;
}
static __device__ __forceinline__ bf16x8 pack_bf8(float4 a, float4 b) {
    union { ushort us[8]; bf16x8 v; } u;
    u.us[0] = f2bf(a.x); u.us[1] = f2bf(a.y); u.us[2] = f2bf(a.z); u.us[3] = f2bf(a.w);
    u.us[4] = f2bf(b.x); u.us[5] = f2bf(b.y); u.us[6] = f2bf(b.z); u.us[7] = f2bf(b.w);
    return u.v;
}

// ---- hist (blocks 0..NCHUNK-1, transposed write) + Bt prep (last 64 blocks) ----
__global__ __launch_bounds__(256) void k_hist(const int* __restrict__ col,
                                              int* __restrict__ gh_t,
                                              const float* __restrict__ W,
                                              const float* __restrict__ skipW,
                                              ushort* __restrict__ Bt) {
    int c = blockIdx.x, t = threadIdx.x;
    if (c >= NCHUNK) {  // prep: Bt[n][k] = bf16(B[k][n])
        int idx = (c - NCHUNK) * 256 + t;
        int k = idx >> 7, n = idx & 127;
        float v = (k < 64) ? W[k * 128 + n] : skipW[(k - 64) * 128 + n];
        Bt[n * 128 + k] = f2bf(v);
        return;
    }
    __shared__ int h[NBUCK_P];
    for (int b = t; b < NBUCK_P; b += 256) h[b] = 0;
    __syncthreads();
    const int4* col4 = (const int4*)col;
    int g0 = c * (CHUNK / 4);
#pragma unroll
    for (int i = 0; i < CHUNK / 1024; ++i) {
        int g4 = g0 + i * 256 + t;
        if (g4 * 4 + 3 < E_EDGES) {
            int4 cc = col4[g4];
            atomicAdd(&h[cc.x >> BUCK_SHIFT], 1);
            atomicAdd(&h[cc.y >> BUCK_SHIFT], 1);
            atomicAdd(&h[cc.z >> BUCK_SHIFT], 1);
            atomicAdd(&h[cc.w >> BUCK_SHIFT], 1);
        } else {
#pragma unroll
            for (int j = 0; j < 4; ++j) {
                int e = g4 * 4 + j;
                if (e < E_EDGES) atomicAdd(&h[col[e] >> BUCK_SHIFT], 1);
            }
        }
    }
    __syncthreads();
    for (int b = t; b < NBUCK_P; b += 256) gh_t[(size_t)b * GH_STRIDE + c] = h[b];
}

// ---- wave-per-bucket exclusive scan over chunks (contiguous, barrier-free) ----
__global__ __launch_bounds__(256) void k_scan_chunks(int* __restrict__ gh_t,
                                                     int* __restrict__ base) {
    int w = threadIdx.x >> 6, l = threadIdx.x & 63;
    int b = blockIdx.x * 4 + w;          // 196 blocks x 4 waves = 784
    if (b >= NBUCK_P) return;
    int* rowp = gh_t + (size_t)b * GH_STRIDE;
    int carry = 0;
#pragma unroll
    for (int i = 0; i < 4; ++i) {        // 4*64 = 256 >= NCHUNK
        int idx = i * 64 + l;
        int v = (idx < NCHUNK) ? rowp[idx] : 0;
        int orig = v;
#pragma unroll
        for (int d = 1; d < 64; d <<= 1) {
            int o = __shfl_up(v, d);
            if (l >= d) v += o;
        }
        if (idx < NCHUNK) rowp[idx] = carry + v - orig;  // exclusive
        carry += __shfl(v, 63);
    }
    if (l == 0 && b < NBUCK) base[b] = carry;            // bucket total
}

// ---- exclusive scan of bucket totals -> bucket bases ----
__global__ __launch_bounds__(1024) void k_scan_bases(int* __restrict__ base,
                                                     int* __restrict__ rowptr) {
    __shared__ int lds[1024];
    int t = threadIdx.x;
    int v = (t < NBUCK) ? base[t] : 0;
    lds[t] = v;
    __syncthreads();
    int val = v;
#pragma unroll
    for (int off = 1; off < 1024; off <<= 1) {
        int add = (t >= off) ? lds[t - off] : 0;
        __syncthreads();
        val += add;
        lds[t] = val;
        __syncthreads();
    }
    if (t < NBUCK) base[t] = val - v;
    if (t == 1023) {
        base[NBUCK] = val;
        rowptr[N_NODES] = val;
    }
}

// ---- scatter edges into bucket-contiguous array (packed), int4 reads ----
__global__ __launch_bounds__(256) void k_scatter_bin(const int* __restrict__ row,
                                                     const int* __restrict__ col,
                                                     const int* __restrict__ gh_t,
                                                     const int* __restrict__ base,
                                                     unsigned int* __restrict__ binned) {
    __shared__ int cur[NBUCK_P];
    int c = blockIdx.x, t = threadIdx.x;
    for (int b = t; b < NBUCK_P; b += 256) {
        int bb = (b < NBUCK) ? base[b] : 0;
        cur[b] = bb + gh_t[(size_t)b * GH_STRIDE + c];
    }
    __syncthreads();
    const int4* col4 = (const int4*)col;
    const int4* row4 = (const int4*)row;
    int g0 = c * (CHUNK / 4);
#pragma unroll
    for (int i = 0; i < CHUNK / 1024; ++i) {
        int g4 = g0 + i * 256 + t;
        if (g4 * 4 + 3 < E_EDGES) {
            int4 cc = col4[g4];
            int4 rr = row4[g4];
            int p;
            p = atomicAdd(&cur[cc.x >> BUCK_SHIFT], 1);
            binned[p] = ((unsigned)(cc.x & 127) << 17) | (unsigned)rr.x;
            p = atomicAdd(&cur[cc.y >> BUCK_SHIFT], 1);
            binned[p] = ((unsigned)(cc.y & 127) << 17) | (unsigned)rr.y;
            p = atomicAdd(&cur[cc.z >> BUCK_SHIFT], 1);
            binned[p] = ((unsigned)(cc.z & 127) << 17) | (unsigned)rr.z;
            p = atomicAdd(&cur[cc.w >> BUCK_SHIFT], 1);
            binned[p] = ((unsigned)(cc.w & 127) << 17) | (unsigned)rr.w;
        } else {
#pragma unroll
            for (int j = 0; j < 4; ++j) {
                int e = g4 * 4 + j;
                if (e < E_EDGES) {
                    int d = col[e], s = row[e];
                    int p = atomicAdd(&cur[d >> BUCK_SHIFT], 1);
                    binned[p] = ((unsigned)(d & 127) << 17) | (unsigned)s;
                }
            }
        }
    }
}

// ---- per-bucket counting sort (shfl scan) -> csr, rowptr, dinv; fused fp8 cast ----
__global__ __launch_bounds__(256) void k_sortbucket(unsigned int* __restrict__ binned,
                                                    const int* __restrict__ base,
                                                    int* __restrict__ rowptr,
                                                    float* __restrict__ dinv,
                                                    const float* __restrict__ x,
                                                    unsigned* __restrict__ xd8) {
    __shared__ unsigned int ebuf[SORT_CAP];
    __shared__ int sbuf[SORT_CAP];
    __shared__ int lcnt[128];
    __shared__ int lptr[128];
    __shared__ float ldinv[128];
    __shared__ int wsum[2];
    int b = blockIdx.x, t = threadIdx.x;
    int i0 = base[b], i1 = base[b + 1];
    int cnt = i1 - i0;
    if (cnt > SORT_CAP) cnt = SORT_CAP;
    int n0 = b << BUCK_SHIFT;
    int nn = min(128, N_NODES - n0);

    for (int k = t; k < cnt; k += 256) ebuf[k] = binned[i0 + k];
    if (t < 128) lcnt[t] = 0;
    __syncthreads();
    for (int k = t; k < cnt; k += 256) atomicAdd(&lcnt[ebuf[k] >> 17], 1);
    __syncthreads();

    // 128-wide exclusive scan via 2-wave shfl
    int myc = 0, val = 0;
    if (t < 128) {
        myc = lcnt[t];
        val = myc;
#pragma unroll
        for (int d = 1; d < 64; d <<= 1) {
            int o = __shfl_up(val, d);
            if ((t & 63) >= d) val += o;
        }
        if ((t & 63) == 63) wsum[t >> 6] = val;
    }
    __syncthreads();
    if (t < 128) {
        if (t >= 64) val += wsum[0];
        int excl = val - myc;
        lptr[t] = excl;
        float dv = rsqrtf((float)myc + 1.0f);  // +1 self loop
        ldinv[t] = dv;
        if (t < nn) {
            rowptr[n0 + t] = i0 + excl;
            dinv[n0 + t] = dv;
        }
    }
    __syncthreads();
    for (int k = t; k < cnt; k += 256) {
        unsigned int e = ebuf[k];
        int j = (int)(e >> 17);
        int p = atomicAdd(&lptr[j], 1);
        sbuf[p] = (int)(e & 0x1FFFF);
    }
    __syncthreads();
    for (int k = t; k < cnt; k += 256) binned[i0 + k] = (unsigned int)sbuf[k];

    // fused cast: this bucket's 128 node rows -> xd8 (fp8 of x*dinv)
#pragma unroll
    for (int it = 0; it < 8; ++it) {
        int idx = it * 256 + t;          // 0..2047
        int nl = idx >> 4, q = idx & 15;
        int c = n0 + nl;
        unsigned w8 = 0;
        if (nl < nn) {
            float4 v = ((const float4*)x)[(size_t)c * 16 + q];
            float d = ldinv[nl];
            w8 = pack_fp8x4(v.x * d, v.y * d, v.z * d, v.w * d);
        }
        xd8[(size_t)c * 16 + q] = w8;
    }
}

// ---- aggregation: 16 lanes per node; fp8 gather (1 line/edge), unroll-8 ----
__global__ __launch_bounds__(256) void k_agg(const unsigned* __restrict__ xd8,
                                             const float* __restrict__ dinv,
                                             const int* __restrict__ rowptr,
                                             const unsigned int* __restrict__ csr,
                                             ushort* __restrict__ u) {
    int t = blockIdx.x * blockDim.x + threadIdx.x;
    if (t >= N_PAD * 16) return;
    int c = t >> 4;
    int q = t & 15;
    if (c >= N_NODES) {
        ushort4 z = {0, 0, 0, 0};
        ((ushort4*)u)[t] = z;
        return;
    }
    float dc = dinv[c];
    float4 acc;
    {
        unsigned w = xd8[t];
        f32x2 lo = __builtin_amdgcn_cvt_pk_f32_fp8((int)w, false);
        f32x2 hi = __builtin_amdgcn_cvt_pk_f32_fp8((int)w, true);
        acc.x = lo.x; acc.y = lo.y; acc.z = hi.x; acc.w = hi.y;
    }
    int i0 = rowptr[c], i1 = rowptr[c + 1];
    int i = i0;
    for (; i + 8 <= i1; i += 8) {
        int s[8];
#pragma unroll
        for (int k = 0; k < 8; ++k) s[k] = (int)csr[i + k];
        unsigned w[8];
#pragma unroll
        for (int k = 0; k < 8; ++k) w[k] = xd8[s[k] * 16 + q];
#pragma unroll
        for (int k = 0; k < 8; ++k) {
            f32x2 lo = __builtin_amdgcn_cvt_pk_f32_fp8((int)w[k], false);
            f32x2 hi = __builtin_amdgcn_cvt_pk_f32_fp8((int)w[k], true);
            acc.x += lo.x; acc.y += lo.y; acc.z += hi.x; acc.w += hi.y;
        }
    }
    for (; i < i1; ++i) {
        unsigned w = xd8[(int)csr[i] * 16 + q];
        f32x2 lo = __builtin_amdgcn_cvt_pk_f32_fp8((int)w, false);
        f32x2 hi = __builtin_amdgcn_cvt_pk_f32_fp8((int)w, true);
        acc.x += lo.x; acc.y += lo.y; acc.z += hi.x; acc.w += hi.y;
    }
    ushort4 o;
    o.x = f2bf(acc.x * dc); o.y = f2bf(acc.y * dc);
    o.z = f2bf(acc.z * dc); o.w = f2bf(acc.w * dc);
    ((ushort4*)u)[t] = o;
}

// ---- MFMA GEMM: pre = [u | bf16(x)] @ Bt^T + bias (bf16 out); BN partials ----
__global__ __launch_bounds__(256) void k_gemm(const ushort* __restrict__ u,
                                              const float* __restrict__ x,
                                              const ushort* __restrict__ Bt,
                                              const float* __restrict__ bias,
                                              ushort* __restrict__ pre,
                                              float* __restrict__ partial) {
    __shared__ float sred[128];
    __shared__ float qred[128];
    int tid = threadIdx.x;
    int wave = tid >> 6, lane = tid & 63;
    int wm = wave >> 1, wn = wave & 1;
    int l15 = lane & 15, quad = lane >> 4;
    int row0 = blockIdx.x * 128 + wm * 64;
    int col0 = wn * 64;

    if (tid < 128) { sred[tid] = 0.f; qred[tid] = 0.f; }
    __syncthreads();

    bf16x8 af[4][4], bf_[4][4];
#pragma unroll
    for (int kc = 0; kc < 2; ++kc) {
        int ko = kc * 32 + quad * 8;
#pragma unroll
        for (int im = 0; im < 4; ++im)
            af[kc][im] = *(const bf16x8*)&u[(size_t)(row0 + im * 16 + l15) * 64 + ko];
    }
#pragma unroll
    for (int kc = 2; kc < 4; ++kc) {
        int ko = (kc - 2) * 32 + quad * 8;
#pragma unroll
        for (int im = 0; im < 4; ++im) {
            int r = row0 + im * 16 + l15;
            float4 v0 = make_float4(0.f, 0.f, 0.f, 0.f);
            float4 v1 = v0;
            if (r < N_NODES) {
                v0 = *(const float4*)&x[(size_t)r * 64 + ko];
                v1 = *(const float4*)&x[(size_t)r * 64 + ko + 4];
            }
            af[kc][im] = pack_bf8(v0, v1);
        }
    }
#pragma unroll
    for (int kc = 0; kc < 4; ++kc)
#pragma unroll
        for (int jn = 0; jn < 4; ++jn)
            bf_[kc][jn] = *(const bf16x8*)&Bt[(size_t)(col0 + jn * 16 + l15) * 128 + kc * 32 + quad * 8];

    f32x4 acc[4][4];
#pragma unroll
    for (int a = 0; a < 4; ++a)
#pragma unroll
        for (int b = 0; b < 4; ++b) acc[a][b] = (f32x4){0.f, 0.f, 0.f, 0.f};

#pragma unroll
    for (int kc = 0; kc < 4; ++kc)
#pragma unroll
        for (int im = 0; im < 4; ++im)
#pragma unroll
            for (int jn = 0; jn < 4; ++jn)
                acc[im][jn] = __builtin_amdgcn_mfma_f32_16x16x32_bf16(
                    af[kc][im], bf_[kc][jn], acc[im][jn], 0, 0, 0);

    int coln[4];
    float bi[4];
#pragma unroll
    for (int jn = 0; jn < 4; ++jn) {
        coln[jn] = col0 + jn * 16 + l15;
        bi[jn] = bias[coln[jn]];
    }
    float lsum[4] = {0.f, 0.f, 0.f, 0.f};
    float lsq[4]  = {0.f, 0.f, 0.f, 0.f};
#pragma unroll
    for (int im = 0; im < 4; ++im) {
        int rbase = row0 + im * 16 + quad * 4;
#pragma unroll
        for (int r = 0; r < 4; ++r) {
            int rowi = rbase + r;
            if (rowi < N_NODES) {
#pragma unroll
                for (int jn = 0; jn < 4; ++jn) {
                    float v = acc[im][jn][r] + bi[jn];
                    pre[(size_t)rowi * 128 + coln[jn]] = f2bf(v);
                    lsum[jn] += v;
                    lsq[jn]  += v * v;
                }
            }
        }
    }
#pragma unroll
    for (int jn = 0; jn < 4; ++jn) {
        atomicAdd(&sred[coln[jn]], lsum[jn]);
        atomicAdd(&qred[coln[jn]], lsq[jn]);
    }
    __syncthreads();
    if (tid < 128) {
        partial[(size_t)blockIdx.x * 256 + tid]       = sred[tid];
        partial[(size_t)blockIdx.x * 256 + 128 + tid] = qred[tid];
    }
}

// ---- reduce 782 partials -> scale/shift (one block per output column) ----
__global__ __launch_bounds__(256) void k_reduce(const float* __restrict__ partial,
                                                const float* __restrict__ gamma,
                                                const float* __restrict__ beta,
                                                float* __restrict__ scaleshift) {
    __shared__ float ls[256], lq[256];
    int j = blockIdx.x;   // 0..127
    int t = threadIdx.x;
    float s = 0.f, q = 0.f;
    for (int p = t; p < NBUCK; p += 256) {
        s += partial[(size_t)p * 256 + j];
        q += partial[(size_t)p * 256 + 128 + j];
    }
    ls[t] = s; lq[t] = q;
    __syncthreads();
#pragma unroll
    for (int off = 128; off > 0; off >>= 1) {
        if (t < off) { ls[t] += ls[t + off]; lq[t] += lq[t + off]; }
        __syncthreads();
    }
    if (t == 0) {
        float mean = ls[0] * (1.0f / N_NODES);
        float var  = lq[0] * (1.0f / N_NODES) - mean * mean;
        float sc   = gamma[j] * rsqrtf(var + 1e-5f);
        scaleshift[j]       = sc;
        scaleshift[128 + j] = beta[j] - mean * sc;
    }
}

// read bf16 pre, write fp32 out
__global__ void k_apply(const ushort* __restrict__ pre, float* __restrict__ out,
                        const float* __restrict__ scaleshift) {
    int t = blockIdx.x * blockDim.x + threadIdx.x;
    if (t >= N_NODES * 32) return;
    int j4 = t & 31;
    ushort4 p = ((const ushort4*)pre)[t];
    float4 sc = ((const float4*)scaleshift)[j4];
    float4 sh = ((const float4*)(scaleshift + 128))[j4];
    float4 v;
    v.x = fmaxf(fmaf(bf2f(p.x), sc.x, sh.x), 0.f);
    v.y = fmaxf(fmaf(bf2f(p.y), sc.y, sh.y), 0.f);
    v.z = fmaxf(fmaf(bf2f(p.z), sc.z, sh.z), 0.f);
    v.w = fmaxf(fmaf(bf2f(p.w), sc.w, sh.w), 0.f);
    ((float4*)out)[t] = v;
}

extern "C" void kernel_launch(void* const* d_in, const int* in_sizes, int n_in,
                              void* d_out, int out_size, void* d_ws, size_t ws_size,
                              hipStream_t stream) {
    const float* x      = (const float*)d_in[0];
    const int*   eidx   = (const int*)d_in[1];
    const float* W      = (const float*)d_in[2];
    const float* bias   = (const float*)d_in[3];
    const float* skipW  = (const float*)d_in[4];
    const float* gamma  = (const float*)d_in[5];
    const float* beta   = (const float*)d_in[6];
    float* out = (float*)d_out;
    float* ws  = (float*)d_ws;

    const int* row = eidx;
    const int* col = eidx + E_EDGES;

    float* scaleshift = ws + OFF_SCALE;
    float* dinv       = ws + OFF_DINV;
    int*   rowptr     = (int*)(ws + OFF_ROWPTR);
    int*   base       = (int*)(ws + OFF_BASE);
    int*   gh_t       = (int*)(ws + OFF_GHIST);
    unsigned int* binned = (unsigned int*)(ws + OFF_BINNED);
    float* partial    = ws + OFF_PART;            // aliases binned (dead after agg)
    ushort* u         = (ushort*)(ws + OFF_U);
    unsigned* xd8     = (unsigned*)(ws + OFF_XD8);  // aliases pre (dead by gemm)
    ushort* pre       = (ushort*)(ws + OFF_PRE);
    ushort* Bt        = (ushort*)(ws + OFF_BT);

    k_hist<<<NCHUNK + 64, 256, 0, stream>>>(col, gh_t, W, skipW, Bt);
    k_scan_chunks<<<(NBUCK_P + 3) / 4, 256, 0, stream>>>(gh_t, base);
    k_scan_bases<<<1, 1024, 0, stream>>>(base, rowptr);
    k_scatter_bin<<<NCHUNK, 256, 0, stream>>>(row, col, gh_t, base, binned);
    k_sortbucket<<<NBUCK, 256, 0, stream>>>(binned, base, rowptr, dinv, x, xd8);
    k_agg<<<(N_PAD * 16 + 255) / 256, 256, 0, stream>>>(xd8, dinv, rowptr, binned, u);
    k_gemm<<<NBUCK, 256, 0, stream>>>(u, x, Bt, bias, pre, partial);
    k_reduce<<<128, 256, 0, stream>>>(partial, gamma, beta, scaleshift);
    k_apply<<<(N_NODES * 32 + 255) / 256, 256, 0, stream>>>(pre, out, scaleshift);
}